// Round 1
// baseline (346.033 us; speedup 1.0000x reference)
//
#include <hip/hip_runtime.h>

#define EMB 2048
#define UDIM 256
#define KTOT 2304
#define NE 64
#define TOPK 8
#define TOK_PER_BLOCK 64
#define NWAVES 8
#define KCHUNK (KTOT / NWAVES)  // 288
#define LDS_STRIDE 65           // 64 + 1 pad -> conflict-free column access

__global__ __launch_bounds__(512, 2)
void gate_kernel(const float* __restrict__ h, const float* __restrict__ u,
                 const float* __restrict__ W, const float* __restrict__ b,
                 float* __restrict__ out) {
  __shared__ float slab[2][TOK_PER_BLOCK * LDS_STRIDE];

  const int lane = threadIdx.x & 63;
  // readfirstlane -> provably wave-uniform so W loads scalarize to s_load
  const int wave = __builtin_amdgcn_readfirstlane(threadIdx.x >> 6);
  const int token_base = blockIdx.x * TOK_PER_BLOCK;
  const int token = token_base + lane;

  float acc[NE];
#pragma unroll
  for (int e = 0; e < NE; ++e) acc[e] = 0.f;

  const int k0 = wave * KCHUNK;
  const int k1 = k0 + KCHUNK;
  const float* __restrict__ hrow = h + (size_t)token * EMB;
  const float* __restrict__ urow = u + (size_t)token * UDIM;

  // Main loop: lane=token, 64 expert accs in VGPRs, W row is wave-uniform
  // (k uniform) -> scalar loads; inner body = 256 v_fmac_f32 per 4 k's.
  for (int k = k0; k < k1; k += 4) {
    float4 x;
    if (k < EMB) {  // uniform branch (k is wave-uniform)
      x = *(const float4*)(hrow + k);
    } else {
      x = *(const float4*)(urow + (k - EMB));
    }
    const float* __restrict__ wr = W + (size_t)k * NE;
#pragma unroll
    for (int j = 0; j < 4; ++j) {
      const float xj = (j == 0) ? x.x : (j == 1) ? x.y : (j == 2) ? x.z : x.w;
#pragma unroll
      for (int e = 0; e < NE; ++e)
        acc[e] = __builtin_fmaf(xj, wr[j * NE + e], acc[e]);
    }
  }

  // ---- cross-wave K-split reduction: 2 slabs, 4 barrier phases ----
  // wave -> (slab = wave&1, phase = wave>>1). stride-65 rows: lane*65+e
  // hits bank (lane+e)%32 -> all 32 banks distinct per step, conflict-free.
  {
    const int slabIdx = wave & 1;
    const int phase = wave >> 1;
    float* srow = &slab[slabIdx][lane * LDS_STRIDE];
    for (int ph = 0; ph < 4; ++ph) {
      if (phase == ph) {
        if (ph == 0) {
#pragma unroll
          for (int e = 0; e < NE; ++e) srow[e] = acc[e];
        } else {
#pragma unroll
          for (int e = 0; e < NE; ++e) srow[e] += acc[e];
        }
      }
      __syncthreads();
    }
    // merge slab1 into slab0 (parallel over all 512 threads)
    for (int i = threadIdx.x; i < TOK_PER_BLOCK * LDS_STRIDE; i += 512)
      slab[0][i] += slab[1][i];
    __syncthreads();
  }

  // ---- epilogue: each wave handles 8 tokens; lane = expert ----
  const float bias = b[lane];
#pragma unroll
  for (int tt = 0; tt < 8; ++tt) {
    const int t = wave * 8 + tt;
    float g = slab[0][t * LDS_STRIDE + lane] + bias;

    // softmax over 64 lanes (butterfly reductions)
    float m = g;
#pragma unroll
    for (int off = 32; off > 0; off >>= 1)
      m = fmaxf(m, __shfl_xor(m, off));
    float p = __expf(g - m);
    float s = p;
#pragma unroll
    for (int off = 32; off > 0; off >>= 1)
      s += __shfl_xor(s, off);
    const float pn = p / s;

    // iterative top-8 argmax; tie-break to lower index (matches top_k)
    float v = pn;
    float topsum = 0.f;
    int sel = 0;
    for (int r = 0; r < TOPK; ++r) {
      float mv = v;
      int mi = lane;
#pragma unroll
      for (int off = 32; off > 0; off >>= 1) {
        const float ov = __shfl_xor(mv, off);
        const int oi = __shfl_xor(mi, off);
        if (ov > mv || (ov == mv && oi < mi)) { mv = ov; mi = oi; }
      }
      topsum += mv;           // wave-uniform result
      if (lane == mi) { sel = 1; v = -1.f; }
    }

    out[(size_t)(token_base + t) * NE + lane] =
        sel ? pn / (topsum + 1e-9f) : 0.f;
  }
}

extern "C" void kernel_launch(void* const* d_in, const int* in_sizes, int n_in,
                              void* d_out, int out_size, void* d_ws, size_t ws_size,
                              hipStream_t stream) {
  const float* h = (const float*)d_in[0];
  const float* u = (const float*)d_in[1];
  const float* W = (const float*)d_in[2];
  const float* b = (const float*)d_in[3];
  float* out = (float*)d_out;

  const int n_tokens = in_sizes[0] / EMB;          // 16384
  const int n_blocks = n_tokens / TOK_PER_BLOCK;   // 256

  hipLaunchKernelGGL(gate_kernel, dim3(n_blocks), dim3(512), 0, stream,
                     h, u, W, b, out);
}

// Round 2
// 285.568 us; speedup vs baseline: 1.2117x; 1.2117x over previous
//
#include <hip/hip_runtime.h>

#define EMB 2048
#define UDIM 256
#define KTOT 2304
#define NE 64
#define TOPK 8
#define TPB 64            // tokens per block (lane = token)
#define KQ 4              // K-split waves
#define EWN 4             // expert-slice waves
#define ESL 16            // experts per wave slice
#define KCH (KTOT / KQ)   // 576
#define LP 65             // slab row stride (64+1) -> conflict-free

__global__ __launch_bounds__(1024, 4)
void gate_fused(const float* __restrict__ h, const float* __restrict__ u,
                const float* __restrict__ W, const float* __restrict__ b,
                float* __restrict__ out) {
  __shared__ float slab[TPB * LP];  // 16.6 KB

  const int lane = threadIdx.x & 63;
  const int wid  = __builtin_amdgcn_readfirstlane(threadIdx.x >> 6);
  const int kq = wid >> 2;   // 0..3 : K-chunk
  const int ew = wid & 3;    // 0..3 : expert slice [16*ew, 16*ew+16)
  const int tok0 = blockIdx.x * TPB;
  const int token = tok0 + lane;

  float acc[ESL];
#pragma unroll
  for (int j = 0; j < ESL; ++j) acc[j] = 0.f;

  const float* __restrict__ xrow_h = h + (size_t)token * EMB;
  const float* __restrict__ xrow_u = u + (size_t)token * UDIM;

  // Inner GEMM segment: x per-lane (its token), W wave-uniform broadcast.
  // Double-buffered 2-k steps: 32 fma per 9 vmem issues, acc stays in VGPRs.
  auto run = [&](const float* __restrict__ xp, const float* __restrict__ wp,
                 int len) {
    float2 xc = *(const float2*)xp;
    float4 wc[2][4];
#pragma unroll
    for (int kk = 0; kk < 2; ++kk)
#pragma unroll
      for (int j = 0; j < 4; ++j)
        wc[kk][j] = *(const float4*)(wp + kk * NE + 4 * j);

    const int iters = len / 2 - 1;
    for (int i = 0; i < iters; ++i) {
      // prefetch next 2-k
      const float* xn_p = xp + 2 * (i + 1);
      const float* wn_p = wp + (size_t)2 * (i + 1) * NE;
      float2 xn = *(const float2*)xn_p;
      float4 wn[2][4];
#pragma unroll
      for (int kk = 0; kk < 2; ++kk)
#pragma unroll
        for (int j = 0; j < 4; ++j)
          wn[kk][j] = *(const float4*)(wn_p + kk * NE + 4 * j);
      // fma current
#pragma unroll
      for (int kk = 0; kk < 2; ++kk) {
        const float xv = kk ? xc.y : xc.x;
#pragma unroll
        for (int j = 0; j < 4; ++j) {
          acc[4 * j + 0] = __builtin_fmaf(xv, wc[kk][j].x, acc[4 * j + 0]);
          acc[4 * j + 1] = __builtin_fmaf(xv, wc[kk][j].y, acc[4 * j + 1]);
          acc[4 * j + 2] = __builtin_fmaf(xv, wc[kk][j].z, acc[4 * j + 2]);
          acc[4 * j + 3] = __builtin_fmaf(xv, wc[kk][j].w, acc[4 * j + 3]);
        }
      }
      xc = xn;
#pragma unroll
      for (int kk = 0; kk < 2; ++kk)
#pragma unroll
        for (int j = 0; j < 4; ++j) wc[kk][j] = wn[kk][j];
    }
    // final 2-k
#pragma unroll
    for (int kk = 0; kk < 2; ++kk) {
      const float xv = kk ? xc.y : xc.x;
#pragma unroll
      for (int j = 0; j < 4; ++j) {
        acc[4 * j + 0] = __builtin_fmaf(xv, wc[kk][j].x, acc[4 * j + 0]);
        acc[4 * j + 1] = __builtin_fmaf(xv, wc[kk][j].y, acc[4 * j + 1]);
        acc[4 * j + 2] = __builtin_fmaf(xv, wc[kk][j].z, acc[4 * j + 2]);
        acc[4 * j + 3] = __builtin_fmaf(xv, wc[kk][j].w, acc[4 * j + 3]);
      }
    }
  };

  const int k0 = kq * KCH;
  const float* wbase = W + (size_t)k0 * NE + ew * ESL;
  if (kq < 3) {
    run(xrow_h + k0, wbase, KCH);
  } else {
    // kq==3 chunk [1728,2304) crosses the h|u boundary at 2048
    run(xrow_h + 1728, wbase, EMB - 1728);                       // 320 k in h
    run(xrow_u, W + (size_t)EMB * NE + ew * ESL, UDIM);          // 256 k in u
  }

  // ---- cross-K reduction into slab: 4 phases, ew-slices disjoint ----
  for (int ph = 0; ph < KQ; ++ph) {
    if (kq == ph) {
      float* srow = slab + lane * LP + ew * ESL;
      if (ph == 0) {
#pragma unroll
        for (int j = 0; j < ESL; ++j) srow[j] = acc[j];
      } else {
#pragma unroll
        for (int j = 0; j < ESL; ++j) srow[j] += acc[j];
      }
    }
    __syncthreads();
  }

  // ---- epilogue: wave wid handles tokens [4*wid, 4*wid+4); lane = expert ----
  const float bias = b[lane];
#pragma unroll
  for (int tt = 0; tt < 4; ++tt) {
    const int t = wid * 4 + tt;
    float g = slab[t * LP + lane] + bias;

    // softmax over 64 lanes
    float m = g;
#pragma unroll
    for (int off = 32; off > 0; off >>= 1)
      m = fmaxf(m, __shfl_xor(m, off));
    float p = __expf(g - m);
    float s = p;
#pragma unroll
    for (int off = 32; off > 0; off >>= 1)
      s += __shfl_xor(s, off);
    const float pn = p / s;

    // iterative top-8 argmax; tie-break to lower index (matches top_k)
    float v = pn;
    float topsum = 0.f;
    int sel = 0;
    for (int r = 0; r < TOPK; ++r) {
      float mv = v;
      int mi = lane;
#pragma unroll
      for (int off = 32; off > 0; off >>= 1) {
        const float ov = __shfl_xor(mv, off);
        const int oi = __shfl_xor(mi, off);
        if (ov > mv || (ov == mv && oi < mi)) { mv = ov; mi = oi; }
      }
      topsum += mv;
      if (lane == mi) { sel = 1; v = -1.f; }
    }

    out[(size_t)(tok0 + t) * NE + lane] =
        sel ? pn / (topsum + 1e-9f) : 0.f;
  }
}

extern "C" void kernel_launch(void* const* d_in, const int* in_sizes, int n_in,
                              void* d_out, int out_size, void* d_ws, size_t ws_size,
                              hipStream_t stream) {
  const float* h = (const float*)d_in[0];
  const float* u = (const float*)d_in[1];
  const float* W = (const float*)d_in[2];
  const float* b = (const float*)d_in[3];
  float* out = (float*)d_out;

  const int n_tokens = in_sizes[0] / EMB;      // 16384
  const int n_blocks = n_tokens / TPB;         // 256

  hipLaunchKernelGGL(gate_fused, dim3(n_blocks), dim3(1024), 0, stream,
                     h, u, W, b, out);
}